// Round 19
// baseline (169.911 us; speedup 1.0000x reference)
//
#include <hip/hip_runtime.h>

// Problem constants (fixed by reference setup_inputs)
#define N_NODES  65536
#define D_FEAT   256
#define N_GRAPHS 256
#define NPG      256
#define N_EDGES  524288
#define CAPX     2560     // support cap (true max = 2048 edges + 256 diag = 2304)
#define EPSF     0.1f
#define MAXIT    100
#define KMAX     4        // sink register slots per sub-thread; 4 subs -> 16/row
#define LOG2E_F  1.4426950408889634f
#define LN2_F    0.6931471805599453f
#define CSCALE   (10.0f * LOG2E_F)   // C * (1/eps) * log2(e) -> base-2 domain
#define MU_VAL   (1.0f / 256.0f + 1e-8f)

// dynamic LDS region (131072 B), time-multiplexed:
//   phase A: m (8 KB) + mT (8 KB) + rowpref (8 KB)
//   phase B/C: tgtb = 256 rows x 512 B bf16, 6-bit XOR granule swizzle
//   epilogue: strip = 128 rows x 256 f32
//   phase D: hist[101][256] packed bf16x2 (drow, wrow) = 103424 B
#define DYN_SIZE  131072

typedef __attribute__((ext_vector_type(8))) short short8;
typedef __attribute__((ext_vector_type(4))) float f32x4;
union U8 { unsigned u[4]; short8 v; };

template<int CTRL>
__device__ __forceinline__ float fdpp(float x){
  int xi = __float_as_int(x);
  int i = __builtin_amdgcn_update_dpp(xi, xi, CTRL, 0xf, 0xf, true);
  return __int_as_float(i);
}
__device__ __forceinline__ float dppSum64(float x){
  x += fdpp<0x111>(x);
  x += fdpp<0x112>(x);
  x += fdpp<0x114>(x);
  x += fdpp<0x118>(x);
  x += fdpp<0x142>(x);
  x += fdpp<0x143>(x);
  return x;
}
__device__ __forceinline__ float bcast63(float x){
  return __int_as_float(__builtin_amdgcn_readlane(__float_as_int(x), 63));
}
#define QXOR1 0xB1
#define QXOR2 0x4E

// int DPP with old=0 — for masked scan steps
template<int CTRL, int RMASK>
__device__ __forceinline__ int idpp0(int x){
  return __builtin_amdgcn_update_dpp(0, x, CTRL, RMASK, 0xf, true);
}
// wave64 inclusive scan (masked row_bcast idiom)
__device__ __forceinline__ int dppScanAdd64(int x){
  x += idpp0<0x111, 0xf>(x);
  x += idpp0<0x112, 0xf>(x);
  x += idpp0<0x114, 0xf>(x);
  x += idpp0<0x118, 0xf>(x);
  x += idpp0<0x142, 0xa>(x);
  x += idpp0<0x143, 0xc>(x);
  return x;
}

__device__ __forceinline__ unsigned bf16r(float f){
  unsigned u = __float_as_uint(f);
  return (u + 0x7FFFu + ((u >> 16) & 1u)) >> 16;
}

// -------- scatter edges + diagonal into per-graph bitmask --------
__global__ __launch_bounds__(256) void k_scatter(const int* __restrict__ ei,
                                                 unsigned* __restrict__ bm){
  int t = blockIdx.x * 256 + threadIdx.x;
  if (t < N_EDGES){
    int uu = ei[t], vv = ei[N_EDGES + t];
    int b = uu >> 8;
    int r = uu & 255;
    int c = vv & 255;
    atomicOr(&bm[(size_t)b * 2048 + r * 8 + (c >> 5)], 1u << (c & 31));
  } else {
    int i = t - N_EDGES;
    if (i < N_NODES){
      int b = i >> 8; int p = i & 255;
      atomicOr(&bm[(size_t)b * 2048 + p * 8 + (p >> 5)], 1u << (p & 31));
    }
  }
}

// ==================== fused per-graph kernel ====================
__global__ __launch_bounds__(1024) void k_graph(
    const unsigned* __restrict__ bm,
    const float* __restrict__ src, const float* __restrict__ tgt,
    float* __restrict__ err_ws, float* __restrict__ wd_ws)
{
  __shared__ float          cs[CAPX];
  __shared__ unsigned short ents[CAPX];
  __shared__ unsigned short cidx[CAPX];
  __shared__ int            rp[257], cp[257];
  __shared__ float          su[256], sv[256];
  extern __shared__ char    dyn[];
  uint2*    tgtb   = (uint2*)dyn;
  unsigned* m      = (unsigned*)dyn;               // phase-A alias
  unsigned* mT     = (unsigned*)(dyn + 8192);      // phase-A alias (transposed)
  int*      rowpref= (int*)(dyn + 16384);          // phase-A alias
  float*    strip  = (float*)dyn;                  // spill alias
  unsigned* histu  = (unsigned*)dyn;               // phase-D alias [101][256]

  int g = blockIdx.x, tid = threadIdx.x;
  int lane = tid & 63, wid = tid >> 6;

  // ---------- Phase A: structure (wave-native) ----------
  for (int i = tid; i < 2048; i += 1024) m[i] = bm[(size_t)g * 2048 + i];
  __syncthreads();

  // A1: transpose 256x256 bitmask via ballot
  {
    int R = wid >> 2, C = wid & 3;
    int row = R * 64 + lane;
    uint2 wp = *reinterpret_cast<const uint2*>(&m[row * 8 + C * 2]);
    unsigned long long colbits = (unsigned long long)wp.x |
                                 ((unsigned long long)wp.y << 32);
    unsigned long long mybal = 0;
    for (int c2 = 0; c2 < 64; c2++){
      unsigned long long bal = __ballot((colbits & 1ull) != 0);
      colbits >>= 1;
      if (lane == c2) mybal = bal;
    }
    int col = C * 64 + lane;
    mT[col * 8 + R * 2]     = (unsigned)mybal;
    mT[col * 8 + R * 2 + 1] = (unsigned)(mybal >> 32);
  }
  __syncthreads();

  // A2: rp scan (wave 0) and cp scan (wave 1)
  if (wid < 2){
    const uint4* W4 = reinterpret_cast<const uint4*>(wid == 0 ? m : mT);
    int* out = (wid == 0) ? rp : cp;
    int r0 = lane * 4;
    int s[4];
    #pragma unroll
    for (int j = 0; j < 4; j++){
      uint4 a = W4[(r0 + j) * 2], b = W4[(r0 + j) * 2 + 1];
      s[j] = __popc(a.x) + __popc(a.y) + __popc(a.z) + __popc(a.w) +
             __popc(b.x) + __popc(b.y) + __popc(b.z) + __popc(b.w);
    }
    int tot = s[0] + s[1] + s[2] + s[3];
    int incl = dppScanAdd64(tot);
    int base = incl - tot;
    out[r0]     = base;
    out[r0 + 1] = base + s[0];
    out[r0 + 2] = base + s[0] + s[1];
    out[r0 + 3] = base + s[0] + s[1] + s[2];
    if (lane == 63) out[256] = (incl > CAPX ? CAPX : incl);
  }
  __syncthreads();

  // A3: ents build + rowpref
  if (tid < 256){
    int r = tid, k = rp[r];
    #pragma unroll
    for (int w = 0; w < 8; w++){
      rowpref[r * 8 + w] = k;
      unsigned bits = m[r * 8 + w];
      while (bits){
        int b = __ffs(bits) - 1; bits &= bits - 1;
        if (k < CAPX) ents[k] = (unsigned short)((r << 8) | (w * 32 + b));
        k++;
      }
    }
  }
  __syncthreads();

  // A4: CSC index list
  if (tid < 256){
    int c = tid;
    int cw2 = c >> 5; unsigned cb2 = 1u << (c & 31);
    int kk = cp[c];
    #pragma unroll
    for (int w = 0; w < 8; w++){
      unsigned bits = mT[c * 8 + w];
      while (bits){
        int b = __ffs(bits) - 1; bits &= bits - 1;
        int r = w * 32 + b;
        int idx = rowpref[r * 8 + cw2] + __popc(m[r * 8 + cw2] & (cb2 - 1u));
        if (kk < CAPX && idx < CAPX) cidx[kk] = (unsigned short)idx;
        kk++;
      }
    }
  }
  __syncthreads();   // m/mT/rowpref dead; tgtb region free

  // ---------- Phase B: tgt -> normalized bf16 in LDS (6-bit swizzle) ----------
  const float4* tbase = reinterpret_cast<const float4*>(tgt + (size_t)g * NPG * D_FEAT);
  const float4* sbase = reinterpret_cast<const float4*>(src + (size_t)g * NPG * D_FEAT);
  for (int r = wid; r < 256; r += 16){
    float4 x = tbase[r * 64 + lane];
    float s = x.x*x.x + x.y*x.y + x.z*x.z + x.w*x.w;
    float inv = 1.0f / (sqrtf(bcast63(dppSum64(s))) + 1e-12f);
    unsigned p0 = bf16r(x.x * inv) | (bf16r(x.y * inv) << 16);
    unsigned p1 = bf16r(x.z * inv) | (bf16r(x.w * inv) << 16);
    tgtb[r * 64 + (lane ^ (r & 7) ^ (((r >> 3) & 7) << 3))] = make_uint2(p0, p1);
  }
  __syncthreads();

  // ---------- Phase C: dense cosine via MFMA ----------
  int G = lane >> 4;
  int l7 = lane & 7;
  int l3 = (lane >> 3) & 1;
  int myrow = wid * 16 + (lane & 15);
  const float4* srow = sbase + myrow * 64;

  float ss = 0.f;
  #pragma unroll
  for (int kk = 0; kk < 8; kk++){
    float4 a0 = srow[kk * 8 + G];
    float4 a1 = srow[kk * 8 + G + 4];
    ss += a0.x*a0.x + a0.y*a0.y + a0.z*a0.z + a0.w*a0.w
        + a1.x*a1.x + a1.y*a1.y + a1.z*a1.z + a1.w*a1.w;
  }
  ss += __shfl_xor(ss, 16);
  ss += __shfl_xor(ss, 32);
  float is = 1.0f / (sqrtf(ss) + 1e-12f);

  U8 af[8];
  #pragma unroll
  for (int kk = 0; kk < 8; kk++){
    float4 a0 = srow[kk * 8 + G];
    float4 a1 = srow[kk * 8 + G + 4];
    af[kk].u[0] = bf16r(a0.x * is) | (bf16r(a0.y * is) << 16);
    af[kk].u[1] = bf16r(a0.z * is) | (bf16r(a0.w * is) << 16);
    af[kk].u[2] = bf16r(a1.x * is) | (bf16r(a1.y * is) << 16);
    af[kk].u[3] = bf16r(a1.z * is) | (bf16r(a1.w * is) << 16);
  }

  f32x4 acc[16];
  #pragma unroll
  for (int nt = 0; nt < 16; nt++) acc[nt] = (f32x4){0.f, 0.f, 0.f, 0.f};

  int off0 = (G ^ l7) << 3;
  int off1 = ((G + 4) ^ l7) << 3;
  #pragma unroll
  for (int nt = 0; nt < 16; nt++){
    int n = nt * 16 + (lane & 15);
    int rowbyte = n << 9;
    int khi = (nt * 2 + l3) & 7;
    f32x4 a = acc[nt];
    #pragma unroll
    for (int kk = 0; kk < 8; kk++){
      int gr = (kk ^ khi) << 6;
      uint2 b0 = *reinterpret_cast<const uint2*>(dyn + rowbyte + gr + off0);
      uint2 b1 = *reinterpret_cast<const uint2*>(dyn + rowbyte + gr + off1);
      U8 bf;
      bf.u[0] = b0.x; bf.u[1] = b0.y; bf.u[2] = b1.x; bf.u[3] = b1.y;
      a = __builtin_amdgcn_mfma_f32_16x16x32_bf16(af[kk].v, bf.v, a, 0, 0, 0);
    }
    acc[nt] = a;
  }
  __syncthreads();   // tgtb dead -> strip region free

  // ---------- spill strips + gather support entries ----------
  int total = rp[256];
  int half_end = rp[128];
  if (wid < 8){
    #pragma unroll
    for (int nt = 0; nt < 16; nt++){
      #pragma unroll
      for (int reg = 0; reg < 4; reg++){
        int rl = wid * 16 + G * 4 + reg;
        strip[rl * 256 + nt * 16 + (lane & 15)] = acc[nt][reg];
      }
    }
  }
  __syncthreads();
  for (int e = tid; e < half_end; e += 1024){
    int r = ents[e] >> 8, c = ents[e] & 255;
    cs[e] = (1.0f - strip[r * 256 + c]) * CSCALE;
  }
  __syncthreads();
  if (wid >= 8){
    #pragma unroll
    for (int nt = 0; nt < 16; nt++){
      #pragma unroll
      for (int reg = 0; reg < 4; reg++){
        int rl = (wid - 8) * 16 + G * 4 + reg;
        strip[rl * 256 + nt * 16 + (lane & 15)] = acc[nt][reg];
      }
    }
  }
  __syncthreads();
  for (int e = half_end + tid; e < total; e += 1024){
    int r = (ents[e] >> 8) - 128, c = ents[e] & 255;
    cs[e] = (1.0f - strip[r * 256 + c]) * CSCALE;
  }
  __syncthreads();

  // ---------- Phase D: Sinkhorn (multiplicative; history -> dead LDS) ----------
  // Per iter: NO reduction waves; sub0 streams (drow, wrow) packed bf16x2
  // into histu[it*256+row]. Post-loop parallel reduction dumps err/wd.
  int row = tid >> 2, sub = tid & 3;

  int rs = rp[row], re = rp[row + 1];
  int rcol[KMAX]; float rw[KMAX], rc2[KMAX];
  #pragma unroll
  for (int k = 0; k < KMAX; k++){
    int idx = rs + sub + 4 * k;
    bool v = idx < re;
    int ai = v ? idx : 0;
    rcol[k] = v ? (ents[ai] & 255) : 0;
    float c2 = v ? cs[ai] : 0.f;
    rw[k]  = v ? exp2f(-c2) : 0.f;
    rc2[k] = c2;
  }
  int rOv = rs + sub + 4 * KMAX;

  int cs0 = cp[row], ce = cp[row + 1];
  int crow[KMAX]; float cw[KMAX];
  #pragma unroll
  for (int k = 0; k < KMAX; k++){
    int idx = cs0 + sub + 4 * k;
    bool v = idx < ce;
    int ai = v ? idx : 0;
    int e = v ? (int)cidx[ai] : 0;
    crow[k] = v ? (ents[e] >> 8) : 0;
    cw[k]   = v ? exp2f(-cs[e]) : 0.f;
  }
  int cOv = cs0 + sub + 4 * KMAX;

  if (tid < 256){ su[tid] = 1.f; sv[tid] = 1.f; }
  __syncthreads();

  const float LOG2_MU = log2f(MU_VAL);
  float a = 0.f, Aprev = 1.f;

  for (int it = 0; it < MAXIT; ++it){
    // ---- row pass ----
    float x0 = sv[rcol[0]] * rw[0];
    float x1 = sv[rcol[1]] * rw[1];
    float x2 = sv[rcol[2]] * rw[2];
    float x3 = sv[rcol[3]] * rw[3];
    float sm   = x0 + x1 + x2 + x3;
    float wsum = x0*rc2[0] + x1*rc2[1] + x2*rc2[2] + x3*rc2[3];
    for (int idx = rOv; idx < re; idx += 4){
      float cv = cs[idx];
      float xo = sv[ents[idx] & 255] * exp2f(-cv);
      sm += xo; wsum += xo * cv;
    }
    sm   += fdpp<QXOR1>(sm);   sm   += fdpp<QXOR2>(sm);
    wsum += fdpp<QXOR1>(wsum); wsum += fdpp<QXOR2>(wsum);
    float Anew = MU_VAL * __builtin_amdgcn_rcpf(sm);
    float an   = LOG2_MU - __builtin_amdgcn_logf(sm);
    if (sub == 0){
      su[row] = Anew;
      // packed history: low16 = drow(it), high16 = wrow(it-1)
      histu[it * 256 + row] = bf16r(fabsf(an - a)) | (bf16r(Aprev * wsum) << 16);
    }
    a = an; Aprev = Anew;
    __syncthreads();   // B1

    // ---- col pass ----
    float y0 = su[crow[0]] * cw[0];
    float y1 = su[crow[1]] * cw[1];
    float y2 = su[crow[2]] * cw[2];
    float y3 = su[crow[3]] * cw[3];
    float csm = y0 + y1 + y2 + y3;
    for (int idx = cOv; idx < ce; idx += 4){
      int e = cidx[idx];
      csm += su[ents[e] >> 8] * exp2f(-cs[e]);
    }
    csm += fdpp<QXOR1>(csm); csm += fdpp<QXOR2>(csm);
    float Bnew = MU_VAL * __builtin_amdgcn_rcpf(csm);
    if (sub == 0) sv[row] = Bnew;
    __syncthreads();   // B2
  }

  // ---- epilogue: wd for the final iteration -> hist slot 100 ----
  {
    float x0 = sv[rcol[0]] * rw[0];
    float x1 = sv[rcol[1]] * rw[1];
    float x2 = sv[rcol[2]] * rw[2];
    float x3 = sv[rcol[3]] * rw[3];
    float wsum = x0*rc2[0] + x1*rc2[1] + x2*rc2[2] + x3*rc2[3];
    for (int idx = rOv; idx < re; idx += 4){
      float cv = cs[idx];
      wsum += sv[ents[idx] & 255] * exp2f(-cv) * cv;
    }
    wsum += fdpp<QXOR1>(wsum); wsum += fdpp<QXOR2>(wsum);
    if (sub == 0) histu[100 * 256 + row] = (bf16r(Aprev * wsum) << 16);
    __syncthreads();
  }

  // ---- parallel history reduction + dump ----
  // hist[it].lo = err(it) for it 0..99 ; hist[it].hi = wd(it-1) for it 1..100
  for (int it = wid; it <= MAXIT; it += 16){
    float esum = 0.f, wsum2 = 0.f;
    #pragma unroll
    for (int j = 0; j < 4; j++){
      unsigned h = histu[it * 256 + j * 64 + lane];
      esum  += __uint_as_float(h << 16);
      wsum2 += __uint_as_float(h & 0xFFFF0000u);
    }
    esum  = dppSum64(esum);
    wsum2 = dppSum64(wsum2);
    if (lane == 63){
      if (it < MAXIT) err_ws[it * N_GRAPHS + g] = esum * (EPSF * LN2_F);
      if (it >= 1)    wd_ws [(it - 1) * N_GRAPHS + g] = wsum2 * (EPSF * LN2_F);
    }
  }
}

// -------- parallel find-T + final mean (one block, 16 waves) --------
__global__ __launch_bounds__(1024) void k_findT_final(
    const float* __restrict__ err_ws, const float* __restrict__ wd_ws,
    float* __restrict__ out)
{
  __shared__ float sSum[MAXIT];
  __shared__ int Tm1s;
  int tid = threadIdx.x, lane = tid & 63, wid = tid >> 6;
  for (int it = wid; it < MAXIT; it += 16){
    float4 v = *reinterpret_cast<const float4*>(&err_ws[it * N_GRAPHS + lane * 4]);
    float s = v.x + v.y + v.z + v.w;
    s = dppSum64(s);
    if (lane == 63) sSum[it] = s;
  }
  __syncthreads();
  if (tid == 0){
    int t = MAXIT - 1;
    for (int it = 0; it < MAXIT; ++it){
      if (sSum[it] * (1.0f / 256.0f) < 0.1f){ t = it; break; }
    }
    Tm1s = t;
  }
  __syncthreads();
  if (wid == 0){
    float4 v = *reinterpret_cast<const float4*>(&wd_ws[Tm1s * N_GRAPHS + lane * 4]);
    float s = v.x + v.y + v.z + v.w;
    s = dppSum64(s);
    if (lane == 63) out[0] = 0.5f * s / 256.0f;
  }
}

extern "C" void kernel_launch(void* const* d_in, const int* in_sizes, int n_in,
                              void* d_out, int out_size, void* d_ws, size_t ws_size,
                              hipStream_t stream)
{
  const float* src = (const float*)d_in[0];
  const float* tgt = (const float*)d_in[1];
  const int*   ei  = (const int*)d_in[2];

  char* ws = (char*)d_ws;
  size_t off = 0;
  auto alloc = [&](size_t bytes) -> char* {
    char* p = ws + off;
    off += (bytes + 255) & ~(size_t)255;
    return p;
  };
  unsigned* bm     = (unsigned*) alloc((size_t)N_GRAPHS * 2048 * 4);
  float*    err_ws = (float*)    alloc((size_t)MAXIT * N_GRAPHS * 4);
  float*    wd_ws  = (float*)    alloc((size_t)MAXIT * N_GRAPHS * 4);

  (void)hipFuncSetAttribute((const void*)k_graph,
                            hipFuncAttributeMaxDynamicSharedMemorySize,
                            DYN_SIZE);

  (void)hipMemsetAsync(bm, 0, (size_t)N_GRAPHS * 2048 * 4, stream);
  k_scatter<<<(N_EDGES + N_NODES + 255) / 256, 256, 0, stream>>>(ei, bm);
  k_graph<<<N_GRAPHS, 1024, DYN_SIZE, stream>>>(bm, src, tgt, err_ws, wd_ws);
  k_findT_final<<<1, 1024, 0, stream>>>(err_ws, wd_ws, (float*)d_out);
}

// Round 20
// 153.201 us; speedup vs baseline: 1.1091x; 1.1091x over previous
//
#include <hip/hip_runtime.h>

// Problem constants (fixed by reference setup_inputs)
#define N_NODES  65536
#define D_FEAT   256
#define N_GRAPHS 256
#define NPG      256
#define N_EDGES  524288
#define CAPX     2560     // support cap (true max = 2048 edges + 256 diag = 2304)
#define EPSF     0.1f
#define MAXIT    100
#define KMAX     4        // sink register slots per sub-thread; 4 subs -> 16/row
#define LOG2E_F  1.4426950408889634f
#define LN2_F    0.6931471805599453f
#define CSCALE   (10.0f * LOG2E_F)   // C * (1/eps) * log2(e) -> base-2 domain
#define MU_VAL   (1.0f / 256.0f + 1e-8f)

// dynamic LDS region (131072 B), time-multiplexed:
//   phase A: m (8 KB) + mT (8 KB) + rowpref (8 KB)
//   phase B/C: tgtb = 256 rows x 512 B bf16, 6-bit XOR granule swizzle
//   epilogue: strip = 128 rows x 256 f32
#define DYN_SIZE  131072

typedef __attribute__((ext_vector_type(8))) short short8;
typedef __attribute__((ext_vector_type(4))) float f32x4;
union U8 { unsigned u[4]; short8 v; };

template<int CTRL>
__device__ __forceinline__ float fdpp(float x){
  int xi = __float_as_int(x);
  int i = __builtin_amdgcn_update_dpp(xi, xi, CTRL, 0xf, 0xf, true);
  return __int_as_float(i);
}
__device__ __forceinline__ float dppSum64(float x){
  x += fdpp<0x111>(x);
  x += fdpp<0x112>(x);
  x += fdpp<0x114>(x);
  x += fdpp<0x118>(x);
  x += fdpp<0x142>(x);
  x += fdpp<0x143>(x);
  return x;
}
__device__ __forceinline__ float bcast63(float x){
  return __int_as_float(__builtin_amdgcn_readlane(__float_as_int(x), 63));
}
#define QXOR1 0xB1
#define QXOR2 0x4E

// int DPP with old=0 — for masked scan steps
template<int CTRL, int RMASK>
__device__ __forceinline__ int idpp0(int x){
  return __builtin_amdgcn_update_dpp(0, x, CTRL, RMASK, 0xf, true);
}
// wave64 inclusive scan (masked row_bcast idiom)
__device__ __forceinline__ int dppScanAdd64(int x){
  x += idpp0<0x111, 0xf>(x);
  x += idpp0<0x112, 0xf>(x);
  x += idpp0<0x114, 0xf>(x);
  x += idpp0<0x118, 0xf>(x);
  x += idpp0<0x142, 0xa>(x);
  x += idpp0<0x143, 0xc>(x);
  return x;
}

__device__ __forceinline__ unsigned bf16r(float f){
  unsigned u = __float_as_uint(f);
  return (u + 0x7FFFu + ((u >> 16) & 1u)) >> 16;
}

// -------- scatter edges + diagonal into per-graph bitmask --------
__global__ __launch_bounds__(256) void k_scatter(const int* __restrict__ ei,
                                                 unsigned* __restrict__ bm){
  int t = blockIdx.x * 256 + threadIdx.x;
  if (t < N_EDGES){
    int uu = ei[t], vv = ei[N_EDGES + t];
    int b = uu >> 8;
    int r = uu & 255;
    int c = vv & 255;
    atomicOr(&bm[(size_t)b * 2048 + r * 8 + (c >> 5)], 1u << (c & 31));
  } else {
    int i = t - N_EDGES;
    if (i < N_NODES){
      int b = i >> 8; int p = i & 255;
      atomicOr(&bm[(size_t)b * 2048 + p * 8 + (p >> 5)], 1u << (p & 31));
    }
  }
}

// ==================== fused per-graph kernel ====================
__global__ __launch_bounds__(1024) void k_graph(
    const unsigned* __restrict__ bm,
    const float* __restrict__ src, const float* __restrict__ tgt,
    float* __restrict__ err_ws, float* __restrict__ wd_ws)
{
  __shared__ float          cs[CAPX];
  __shared__ unsigned short ents[CAPX];
  __shared__ unsigned short cidx[CAPX];
  __shared__ int            rp[257], cp[257];
  __shared__ float          su[256], sv[256], drow[256], wrow[256];
  __shared__ float          sErr[MAXIT], sWd[MAXIT];
  extern __shared__ char    dyn[];
  uint2*    tgtb   = (uint2*)dyn;
  unsigned* m      = (unsigned*)dyn;               // phase-A alias
  unsigned* mT     = (unsigned*)(dyn + 8192);      // phase-A alias (transposed)
  int*      rowpref= (int*)(dyn + 16384);          // phase-A alias
  float*    strip  = (float*)dyn;                  // spill alias

  int g = blockIdx.x, tid = threadIdx.x;
  int lane = tid & 63, wid = tid >> 6;

  // ---------- Phase A: structure (wave-native) ----------
  for (int i = tid; i < 2048; i += 1024) m[i] = bm[(size_t)g * 2048 + i];
  __syncthreads();

  // A1: transpose 256x256 bitmask via ballot
  {
    int R = wid >> 2, C = wid & 3;
    int row = R * 64 + lane;
    uint2 wp = *reinterpret_cast<const uint2*>(&m[row * 8 + C * 2]);
    unsigned long long colbits = (unsigned long long)wp.x |
                                 ((unsigned long long)wp.y << 32);
    unsigned long long mybal = 0;
    for (int c2 = 0; c2 < 64; c2++){
      unsigned long long bal = __ballot((colbits & 1ull) != 0);
      colbits >>= 1;
      if (lane == c2) mybal = bal;
    }
    int col = C * 64 + lane;
    mT[col * 8 + R * 2]     = (unsigned)mybal;
    mT[col * 8 + R * 2 + 1] = (unsigned)(mybal >> 32);
  }
  __syncthreads();

  // A2: rp scan (wave 0) and cp scan (wave 1)
  if (wid < 2){
    const uint4* W4 = reinterpret_cast<const uint4*>(wid == 0 ? m : mT);
    int* out = (wid == 0) ? rp : cp;
    int r0 = lane * 4;
    int s[4];
    #pragma unroll
    for (int j = 0; j < 4; j++){
      uint4 a = W4[(r0 + j) * 2], b = W4[(r0 + j) * 2 + 1];
      s[j] = __popc(a.x) + __popc(a.y) + __popc(a.z) + __popc(a.w) +
             __popc(b.x) + __popc(b.y) + __popc(b.z) + __popc(b.w);
    }
    int tot = s[0] + s[1] + s[2] + s[3];
    int incl = dppScanAdd64(tot);
    int base = incl - tot;
    out[r0]     = base;
    out[r0 + 1] = base + s[0];
    out[r0 + 2] = base + s[0] + s[1];
    out[r0 + 3] = base + s[0] + s[1] + s[2];
    if (lane == 63) out[256] = (incl > CAPX ? CAPX : incl);
  }
  __syncthreads();

  // A3: ents build + rowpref
  if (tid < 256){
    int r = tid, k = rp[r];
    #pragma unroll
    for (int w = 0; w < 8; w++){
      rowpref[r * 8 + w] = k;
      unsigned bits = m[r * 8 + w];
      while (bits){
        int b = __ffs(bits) - 1; bits &= bits - 1;
        if (k < CAPX) ents[k] = (unsigned short)((r << 8) | (w * 32 + b));
        k++;
      }
    }
  }
  __syncthreads();

  // A4: CSC index list
  if (tid < 256){
    int c = tid;
    int cw2 = c >> 5; unsigned cb2 = 1u << (c & 31);
    int kk = cp[c];
    #pragma unroll
    for (int w = 0; w < 8; w++){
      unsigned bits = mT[c * 8 + w];
      while (bits){
        int b = __ffs(bits) - 1; bits &= bits - 1;
        int r = w * 32 + b;
        int idx = rowpref[r * 8 + cw2] + __popc(m[r * 8 + cw2] & (cb2 - 1u));
        if (kk < CAPX && idx < CAPX) cidx[kk] = (unsigned short)idx;
        kk++;
      }
    }
  }
  __syncthreads();   // m/mT/rowpref dead; tgtb region free

  // ---------- Phase B: tgt -> normalized bf16 in LDS (6-bit swizzle) ----------
  const float4* tbase = reinterpret_cast<const float4*>(tgt + (size_t)g * NPG * D_FEAT);
  const float4* sbase = reinterpret_cast<const float4*>(src + (size_t)g * NPG * D_FEAT);
  for (int r = wid; r < 256; r += 16){
    float4 x = tbase[r * 64 + lane];
    float s = x.x*x.x + x.y*x.y + x.z*x.z + x.w*x.w;
    float inv = 1.0f / (sqrtf(bcast63(dppSum64(s))) + 1e-12f);
    unsigned p0 = bf16r(x.x * inv) | (bf16r(x.y * inv) << 16);
    unsigned p1 = bf16r(x.z * inv) | (bf16r(x.w * inv) << 16);
    tgtb[r * 64 + (lane ^ (r & 7) ^ (((r >> 3) & 7) << 3))] = make_uint2(p0, p1);
  }
  __syncthreads();

  // ---------- Phase C: dense cosine via MFMA ----------
  // src row register-cached across norm pass and fragment pass (one read).
  int G = lane >> 4;
  int l7 = lane & 7;
  int l3 = (lane >> 3) & 1;
  int myrow = wid * 16 + (lane & 15);
  const float4* srow = sbase + myrow * 64;

  float4 a0r[8], a1r[8];
  float ss = 0.f;
  #pragma unroll
  for (int kk = 0; kk < 8; kk++){
    a0r[kk] = srow[kk * 8 + G];
    a1r[kk] = srow[kk * 8 + G + 4];
    ss += a0r[kk].x*a0r[kk].x + a0r[kk].y*a0r[kk].y
        + a0r[kk].z*a0r[kk].z + a0r[kk].w*a0r[kk].w
        + a1r[kk].x*a1r[kk].x + a1r[kk].y*a1r[kk].y
        + a1r[kk].z*a1r[kk].z + a1r[kk].w*a1r[kk].w;
  }
  ss += __shfl_xor(ss, 16);
  ss += __shfl_xor(ss, 32);
  float is = 1.0f / (sqrtf(ss) + 1e-12f);

  U8 af[8];
  #pragma unroll
  for (int kk = 0; kk < 8; kk++){
    af[kk].u[0] = bf16r(a0r[kk].x * is) | (bf16r(a0r[kk].y * is) << 16);
    af[kk].u[1] = bf16r(a0r[kk].z * is) | (bf16r(a0r[kk].w * is) << 16);
    af[kk].u[2] = bf16r(a1r[kk].x * is) | (bf16r(a1r[kk].y * is) << 16);
    af[kk].u[3] = bf16r(a1r[kk].z * is) | (bf16r(a1r[kk].w * is) << 16);
  }

  f32x4 acc[16];
  #pragma unroll
  for (int nt = 0; nt < 16; nt++) acc[nt] = (f32x4){0.f, 0.f, 0.f, 0.f};

  int off0 = (G ^ l7) << 3;
  int off1 = ((G + 4) ^ l7) << 3;
  #pragma unroll
  for (int nt = 0; nt < 16; nt++){
    int n = nt * 16 + (lane & 15);
    int rowbyte = n << 9;
    int khi = (nt * 2 + l3) & 7;
    f32x4 a = acc[nt];
    #pragma unroll
    for (int kk = 0; kk < 8; kk++){
      int gr = (kk ^ khi) << 6;
      uint2 b0 = *reinterpret_cast<const uint2*>(dyn + rowbyte + gr + off0);
      uint2 b1 = *reinterpret_cast<const uint2*>(dyn + rowbyte + gr + off1);
      U8 bf;
      bf.u[0] = b0.x; bf.u[1] = b0.y; bf.u[2] = b1.x; bf.u[3] = b1.y;
      a = __builtin_amdgcn_mfma_f32_16x16x32_bf16(af[kk].v, bf.v, a, 0, 0, 0);
    }
    acc[nt] = a;
  }
  __syncthreads();   // tgtb dead -> strip region free

  // ---------- spill strips + gather support entries ----------
  int total = rp[256];
  int half_end = rp[128];
  if (wid < 8){
    #pragma unroll
    for (int nt = 0; nt < 16; nt++){
      #pragma unroll
      for (int reg = 0; reg < 4; reg++){
        int rl = wid * 16 + G * 4 + reg;
        strip[rl * 256 + nt * 16 + (lane & 15)] = acc[nt][reg];
      }
    }
  }
  __syncthreads();
  for (int e = tid; e < half_end; e += 1024){
    int r = ents[e] >> 8, c = ents[e] & 255;
    cs[e] = (1.0f - strip[r * 256 + c]) * CSCALE;
  }
  __syncthreads();
  if (wid >= 8){
    #pragma unroll
    for (int nt = 0; nt < 16; nt++){
      #pragma unroll
      for (int reg = 0; reg < 4; reg++){
        int rl = (wid - 8) * 16 + G * 4 + reg;
        strip[rl * 256 + nt * 16 + (lane & 15)] = acc[nt][reg];
      }
    }
  }
  __syncthreads();
  for (int e = half_end + tid; e < total; e += 1024){
    int r = (ents[e] >> 8) - 128, c = ents[e] & 255;
    cs[e] = (1.0f - strip[r * 256 + c]) * CSCALE;
  }
  __syncthreads();

  // ---------- Phase D: Sinkhorn (multiplicative domain) ----------
  int row = tid >> 2, sub = tid & 3;

  int rs = rp[row], re = rp[row + 1];
  int rcol[KMAX]; float rw[KMAX], rc2[KMAX];
  #pragma unroll
  for (int k = 0; k < KMAX; k++){
    int idx = rs + sub + 4 * k;
    bool v = idx < re;
    int ai = v ? idx : 0;
    rcol[k] = v ? (ents[ai] & 255) : 0;
    float c2 = v ? cs[ai] : 0.f;
    rw[k]  = v ? exp2f(-c2) : 0.f;
    rc2[k] = c2;
  }
  int rOv = rs + sub + 4 * KMAX;

  int cs0 = cp[row], ce = cp[row + 1];
  int crow[KMAX]; float cw[KMAX];
  #pragma unroll
  for (int k = 0; k < KMAX; k++){
    int idx = cs0 + sub + 4 * k;
    bool v = idx < ce;
    int ai = v ? idx : 0;
    int e = v ? (int)cidx[ai] : 0;
    crow[k] = v ? (ents[e] >> 8) : 0;
    cw[k]   = v ? exp2f(-cs[e]) : 0.f;
  }
  int cOv = cs0 + sub + 4 * KMAX;

  if (tid < 256){ su[tid] = 1.f; sv[tid] = 1.f; }
  __syncthreads();

  const float LOG2_MU = log2f(MU_VAL);
  float a = 0.f, Aprev = 1.f;

  for (int it = 0; it < MAXIT; ++it){
    float x0 = sv[rcol[0]] * rw[0];
    float x1 = sv[rcol[1]] * rw[1];
    float x2 = sv[rcol[2]] * rw[2];
    float x3 = sv[rcol[3]] * rw[3];
    float sm   = x0 + x1 + x2 + x3;
    float wsum = x0*rc2[0] + x1*rc2[1] + x2*rc2[2] + x3*rc2[3];
    for (int idx = rOv; idx < re; idx += 4){
      float cv = cs[idx];
      float xo = sv[ents[idx] & 255] * exp2f(-cv);
      sm += xo; wsum += xo * cv;
    }
    sm   += fdpp<QXOR1>(sm);   sm   += fdpp<QXOR2>(sm);
    wsum += fdpp<QXOR1>(wsum); wsum += fdpp<QXOR2>(wsum);
    float Anew = MU_VAL * __builtin_amdgcn_rcpf(sm);
    float an   = LOG2_MU - __builtin_amdgcn_logf(sm);
    if (sub == 0){
      su[row]   = Anew;
      drow[row] = fabsf(an - a);
      wrow[row] = Aprev * wsum;
    }
    a = an; Aprev = Anew;
    __syncthreads();

    if (tid < 64){
      float e4 = drow[tid] + drow[tid + 64] + drow[tid + 128] + drow[tid + 192];
      e4 = dppSum64(e4);
      if (lane == 63) sErr[it] = e4 * (EPSF * LN2_F);
    } else if (tid < 128 && it > 0){
      int l = tid - 64;
      float w4 = wrow[l] + wrow[l + 64] + wrow[l + 128] + wrow[l + 192];
      w4 = dppSum64(w4);
      if (lane == 63) sWd[it - 1] = w4 * (EPSF * LN2_F);
    }

    float y0 = su[crow[0]] * cw[0];
    float y1 = su[crow[1]] * cw[1];
    float y2 = su[crow[2]] * cw[2];
    float y3 = su[crow[3]] * cw[3];
    float csm = y0 + y1 + y2 + y3;
    for (int idx = cOv; idx < ce; idx += 4){
      int e = cidx[idx];
      csm += su[ents[e] >> 8] * exp2f(-cs[e]);
    }
    csm += fdpp<QXOR1>(csm); csm += fdpp<QXOR2>(csm);
    float Bnew = MU_VAL * __builtin_amdgcn_rcpf(csm);
    if (sub == 0) sv[row] = Bnew;
    __syncthreads();
  }

  {
    float x0 = sv[rcol[0]] * rw[0];
    float x1 = sv[rcol[1]] * rw[1];
    float x2 = sv[rcol[2]] * rw[2];
    float x3 = sv[rcol[3]] * rw[3];
    float wsum = x0*rc2[0] + x1*rc2[1] + x2*rc2[2] + x3*rc2[3];
    for (int idx = rOv; idx < re; idx += 4){
      float cv = cs[idx];
      wsum += sv[ents[idx] & 255] * exp2f(-cv) * cv;
    }
    wsum += fdpp<QXOR1>(wsum); wsum += fdpp<QXOR2>(wsum);
    if (sub == 0) wrow[row] = Aprev * wsum;
    __syncthreads();
    if (tid < 64){
      float w4 = wrow[tid] + wrow[tid + 64] + wrow[tid + 128] + wrow[tid + 192];
      w4 = dppSum64(w4);
      if (lane == 63) sWd[MAXIT - 1] = w4 * (EPSF * LN2_F);
    }
    __syncthreads();
  }

  for (int it = tid; it < MAXIT; it += 1024){
    err_ws[it * N_GRAPHS + g] = sErr[it];
    wd_ws [it * N_GRAPHS + g] = sWd[it];
  }
}

// -------- parallel find-T + final mean (one block, 16 waves) --------
__global__ __launch_bounds__(1024) void k_findT_final(
    const float* __restrict__ err_ws, const float* __restrict__ wd_ws,
    float* __restrict__ out)
{
  __shared__ float sSum[MAXIT];
  __shared__ int Tm1s;
  int tid = threadIdx.x, lane = tid & 63, wid = tid >> 6;
  for (int it = wid; it < MAXIT; it += 16){
    float4 v = *reinterpret_cast<const float4*>(&err_ws[it * N_GRAPHS + lane * 4]);
    float s = v.x + v.y + v.z + v.w;
    s = dppSum64(s);
    if (lane == 63) sSum[it] = s;
  }
  __syncthreads();
  if (tid == 0){
    int t = MAXIT - 1;
    for (int it = 0; it < MAXIT; ++it){
      if (sSum[it] * (1.0f / 256.0f) < 0.1f){ t = it; break; }
    }
    Tm1s = t;
  }
  __syncthreads();
  if (wid == 0){
    float4 v = *reinterpret_cast<const float4*>(&wd_ws[Tm1s * N_GRAPHS + lane * 4]);
    float s = v.x + v.y + v.z + v.w;
    s = dppSum64(s);
    if (lane == 63) out[0] = 0.5f * s / 256.0f;
  }
}

extern "C" void kernel_launch(void* const* d_in, const int* in_sizes, int n_in,
                              void* d_out, int out_size, void* d_ws, size_t ws_size,
                              hipStream_t stream)
{
  const float* src = (const float*)d_in[0];
  const float* tgt = (const float*)d_in[1];
  const int*   ei  = (const int*)d_in[2];

  char* ws = (char*)d_ws;
  size_t off = 0;
  auto alloc = [&](size_t bytes) -> char* {
    char* p = ws + off;
    off += (bytes + 255) & ~(size_t)255;
    return p;
  };
  unsigned* bm     = (unsigned*) alloc((size_t)N_GRAPHS * 2048 * 4);
  float*    err_ws = (float*)    alloc((size_t)MAXIT * N_GRAPHS * 4);
  float*    wd_ws  = (float*)    alloc((size_t)MAXIT * N_GRAPHS * 4);

  (void)hipFuncSetAttribute((const void*)k_graph,
                            hipFuncAttributeMaxDynamicSharedMemorySize,
                            DYN_SIZE);

  (void)hipMemsetAsync(bm, 0, (size_t)N_GRAPHS * 2048 * 4, stream);
  k_scatter<<<(N_EDGES + N_NODES + 255) / 256, 256, 0, stream>>>(ei, bm);
  k_graph<<<N_GRAPHS, 1024, DYN_SIZE, stream>>>(bm, src, tgt, err_ws, wd_ws);
  k_findT_final<<<1, 1024, 0, stream>>>(err_ws, wd_ws, (float*)d_out);
}